// Round 13
// baseline (970.632 us; speedup 1.0000x reference)
//
#include <hip/hip_runtime.h>
#include <float.h>

#define NB 16
#define NP 1024
#define NROW (NB*NP)

// ---------------------------------------------------------------- init (stats+pool buffers; pmax/pmin alias pq, init AFTER gather L4)
__global__ void k_init(float* colsum, float* colsq, float* pmax, float* pmin) {
    int i = blockIdx.x * 256 + threadIdx.x;          // grid 512 -> i < 131072
    if (i < 1024) { colsum[i] = 0.f; colsq[i] = 0.f; }
    pmax[i] = -FLT_MAX;
    pmin[i] =  FLT_MAX;
}

// ---------------------------------------------------------------- weight prep
__global__ void k_prep(const float* __restrict__ W, const float* __restrict__ b,
                       float* __restrict__ wc, float* __restrict__ b2, int d, int dout) {
    int n2 = 2 * dout;
    int i = blockIdx.x * 256 + threadIdx.x;
    if (i < d * n2) {
        int kk = i / n2, c = i % n2;
        wc[i] = (c < dout) ? (W[kk * dout + c] - W[(kk + d) * dout + c])
                           : W[(kk + d) * dout + (c - dout)];
    }
    if (i < n2) b2[i] = (i < dout) ? b[i] : 0.f;
}

// ---------------------------------------------------------------- squared norms
__global__ void k_sqnorm(const float* __restrict__ x, int stride, int D, float* __restrict__ sq) {
    int row = blockIdx.x * 4 + (threadIdx.x >> 6);
    int lane = threadIdx.x & 63;
    const float* xr = x + (size_t)row * stride;
    float s = 0.f;
    for (int kk = lane; kk < D; kk += 64) { float v = xr[kk]; s += v * v; }
    for (int o = 32; o; o >>= 1) s += __shfl_down(s, o);
    if (lane == 0) sq[row] = s;
}

// ---------------------------------------------------------------- float -> order-preserving u32
__device__ inline unsigned ford(float f) {
    unsigned u = __float_as_uint(f);
    return (u & 0x80000000u) ? ~u : (u | 0x80000000u);
}

// 4 FMAs: c (float4) += s * b
#define FMA4(c_, s_, b_) do { \
    (c_).x += (s_)*(b_).x; (c_).y += (s_)*(b_).y; (c_).z += (s_)*(b_).z; (c_).w += (s_)*(b_).w; \
} while (0)

#define FMA16(a, bv) do { \
    acc[0].x += (a).x*(bv).x; acc[0].y += (a).x*(bv).y; acc[0].z += (a).x*(bv).z; acc[0].w += (a).x*(bv).w; \
    acc[1].x += (a).y*(bv).x; acc[1].y += (a).y*(bv).y; acc[1].z += (a).y*(bv).z; acc[1].w += (a).y*(bv).w; \
    acc[2].x += (a).z*(bv).x; acc[2].y += (a).z*(bv).y; acc[2].z += (a).z*(bv).z; acc[2].w += (a).z*(bv).w; \
    acc[3].x += (a).w*(bv).x; acc[3].y += (a).w*(bv).y; acc[3].z += (a).w*(bv).z; acc[3].w += (a).w*(bv).w; \
} while (0)

// ---------------------------------------------------------------- distance tile GEMM, 128x128 tile, split 2x2 sub-tiles (4+4)
// dist[r][j] = sq[j] - 2 * x_r . x_j ; grid (8 j-tiles, 8 row-tiles, 8 clouds), block 256.
// thread covers rows {ty*4, 64+ty*4}+0..3 and cols {tx*4, 64+tx*4}+0..3 -> 2-way-free LDS reads.
template<int D>
__global__ __launch_bounds__(256) void k_dist(const float* __restrict__ x, int stride,
                                              const float* __restrict__ sq,
                                              float* __restrict__ dist, int pass) {
    constexpr int KC = (D < 32) ? D : 32;
    __shared__ __align__(16) float At[KC * 132];
    __shared__ __align__(16) float Bt[KC * 132];
    const int tid = threadIdx.x;
    const int tx = tid & 15, ty = tid >> 4;
    const int j0 = blockIdx.x * 128;
    const int r0 = blockIdx.y * 128;
    const int bb = pass * 8 + blockIdx.z;

    float4 a_ll[4] = {}, a_lh[4] = {}, a_hl[4] = {}, a_hh[4] = {};
    for (int k0 = 0; k0 < D; k0 += KC) {
        __syncthreads();
        if constexpr (KC % 4 == 0) {
            constexpr int K4 = KC / 4;
            for (int e = tid; e < 128 * K4; e += 256) {
                int rr = e / K4, kq = e % K4;
                float4 v = *(const float4*)(x + (size_t)(bb * NP + r0 + rr) * stride + k0 + kq * 4);
                At[(4 * kq + 0) * 132 + rr] = v.x;
                At[(4 * kq + 1) * 132 + rr] = v.y;
                At[(4 * kq + 2) * 132 + rr] = v.z;
                At[(4 * kq + 3) * 132 + rr] = v.w;
            }
            for (int e = tid; e < 128 * K4; e += 256) {
                int jj = e / K4, kq = e % K4;
                float4 v = *(const float4*)(x + (size_t)(bb * NP + j0 + jj) * stride + k0 + kq * 4);
                Bt[(4 * kq + 0) * 132 + jj] = v.x;
                Bt[(4 * kq + 1) * 132 + jj] = v.y;
                Bt[(4 * kq + 2) * 132 + jj] = v.z;
                Bt[(4 * kq + 3) * 132 + jj] = v.w;
            }
        } else {
            for (int e = tid; e < 128 * KC; e += 256) {
                int rr = e / KC, kk = e % KC;
                At[kk * 132 + rr] = x[(size_t)(bb * NP + r0 + rr) * stride + k0 + kk];
            }
            for (int e = tid; e < 128 * KC; e += 256) {
                int jj = e / KC, kk = e % KC;
                Bt[kk * 132 + jj] = x[(size_t)(bb * NP + j0 + jj) * stride + k0 + kk];
            }
        }
        __syncthreads();
#pragma unroll 4
        for (int kk = 0; kk < KC; kk++) {
            float4 alo = *(const float4*)&At[kk * 132 + ty * 4];
            float4 ahi = *(const float4*)&At[kk * 132 + 64 + ty * 4];
            float4 blo = *(const float4*)&Bt[kk * 132 + tx * 4];
            float4 bhi = *(const float4*)&Bt[kk * 132 + 64 + tx * 4];
            FMA4(a_ll[0], alo.x, blo); FMA4(a_lh[0], alo.x, bhi);
            FMA4(a_ll[1], alo.y, blo); FMA4(a_lh[1], alo.y, bhi);
            FMA4(a_ll[2], alo.z, blo); FMA4(a_lh[2], alo.z, bhi);
            FMA4(a_ll[3], alo.w, blo); FMA4(a_lh[3], alo.w, bhi);
            FMA4(a_hl[0], ahi.x, blo); FMA4(a_hh[0], ahi.x, bhi);
            FMA4(a_hl[1], ahi.y, blo); FMA4(a_hh[1], ahi.y, bhi);
            FMA4(a_hl[2], ahi.z, blo); FMA4(a_hh[2], ahi.z, bhi);
            FMA4(a_hl[3], ahi.w, blo); FMA4(a_hh[3], ahi.w, bhi);
        }
    }
    float4 sqlo = *(const float4*)(sq + bb * NP + j0 + tx * 4);
    float4 sqhi = *(const float4*)(sq + bb * NP + j0 + 64 + tx * 4);
#pragma unroll
    for (int ri = 0; ri < 4; ri++) {
        float* dlo = dist + (size_t)(blockIdx.z * NP + r0 + ty * 4 + ri) * NP + j0;
        float* dhi = dist + (size_t)(blockIdx.z * NP + r0 + 64 + ty * 4 + ri) * NP + j0;
        float4 o;
        o.x = sqlo.x - 2.f * a_ll[ri].x; o.y = sqlo.y - 2.f * a_ll[ri].y;
        o.z = sqlo.z - 2.f * a_ll[ri].z; o.w = sqlo.w - 2.f * a_ll[ri].w;
        *(float4*)(dlo + tx * 4) = o;
        o.x = sqhi.x - 2.f * a_lh[ri].x; o.y = sqhi.y - 2.f * a_lh[ri].y;
        o.z = sqhi.z - 2.f * a_lh[ri].z; o.w = sqhi.w - 2.f * a_lh[ri].w;
        *(float4*)(dlo + 64 + tx * 4) = o;
        o.x = sqlo.x - 2.f * a_hl[ri].x; o.y = sqlo.y - 2.f * a_hl[ri].y;
        o.z = sqlo.z - 2.f * a_hl[ri].z; o.w = sqlo.w - 2.f * a_hl[ri].w;
        *(float4*)(dhi + tx * 4) = o;
        o.x = sqhi.x - 2.f * a_hh[ri].x; o.y = sqhi.y - 2.f * a_hh[ri].y;
        o.z = sqhi.z - 2.f * a_hh[ri].z; o.w = sqhi.w - 2.f * a_hh[ri].w;
        *(float4*)(dhi + 64 + tx * 4) = o;
    }
}

// ---------------------------------------------------------------- top-20 select: one wave per row
__global__ __launch_bounds__(256) void k_select(const float* __restrict__ dist,
                                                int* __restrict__ idxout, int pass) {
    const int w = threadIdx.x >> 6, lane = threadIdx.x & 63;
    const int rowlocal = blockIdx.x * 4 + w;          // 0..8191 per pass
    const size_t base = (size_t)rowlocal * NP;
    const int growrow = pass * 8 * NP + rowlocal;

    unsigned long long pk[16];
    const float4* dp = (const float4*)(dist + base + lane * 16);
#pragma unroll
    for (int q = 0; q < 4; q++) {
        float4 v = dp[q];
        int jb = lane * 16 + q * 4;
        pk[q * 4 + 0] = ((unsigned long long)ford(v.x) << 32) | (unsigned)(jb + 0);
        pk[q * 4 + 1] = ((unsigned long long)ford(v.y) << 32) | (unsigned)(jb + 1);
        pk[q * 4 + 2] = ((unsigned long long)ford(v.z) << 32) | (unsigned)(jb + 2);
        pk[q * 4 + 3] = ((unsigned long long)ford(v.w) << 32) | (unsigned)(jb + 3);
    }
    unsigned msk = 0;
#pragma unroll 1
    for (int it = 0; it < 20; it++) {
        unsigned long long m = 0xFFFFFFFFFFFFFFFFULL;
#pragma unroll
        for (int t = 0; t < 16; t++) {
            unsigned long long v = (msk & (1u << t)) ? 0xFFFFFFFFFFFFFFFFULL : pk[t];
            m = (v < m) ? v : m;
        }
#pragma unroll
        for (int o = 32; o; o >>= 1) {
            unsigned long long v = __shfl_xor(m, o);
            m = (v < m) ? v : m;
        }
        unsigned wj = (unsigned)(m & 0xFFFFFFFFu);
        if (lane == (int)(wj >> 4)) msk |= 1u << (wj & 15u);
        if (lane == 0) idxout[(size_t)growrow * 20 + it] = (int)wj;
    }
}

// ---------------------------------------------------------------- p/q GEMM (64-tile 4x4; small, unchanged)
template<int D, int DOUT>
__global__ __launch_bounds__(256) void k_gemm_pq(const float* __restrict__ x, int stride,
                                                 const float* __restrict__ wc, const float* __restrict__ b2,
                                                 float* __restrict__ pq) {
    constexpr int N2 = 2 * DOUT;
    constexpr int KC = (D > 64) ? 64 : D;
    __shared__ __align__(16) float At[KC * 68];
    __shared__ __align__(16) float Bs[KC * 64];
    const int tid = threadIdx.x;
    const int tx = tid & 15, ty = tid >> 4;
    const int r0 = blockIdx.x * 64;
    const int c0 = blockIdx.y * 64;

    float4 acc[4] = {};
    for (int k0 = 0; k0 < D; k0 += KC) {
        __syncthreads();
        if constexpr (KC % 4 == 0) {
            constexpr int K4 = KC / 4;
            for (int e = tid; e < 64 * K4; e += 256) {
                int rr = e / K4, kq = e % K4;
                float4 v = *(const float4*)(x + (size_t)(r0 + rr) * stride + k0 + kq * 4);
                At[(4 * kq + 0) * 68 + rr] = v.x;
                At[(4 * kq + 1) * 68 + rr] = v.y;
                At[(4 * kq + 2) * 68 + rr] = v.z;
                At[(4 * kq + 3) * 68 + rr] = v.w;
            }
        } else {
            for (int e = tid; e < 64 * KC; e += 256) {
                int rr = e / KC, kk = e % KC;
                At[kk * 68 + rr] = x[(size_t)(r0 + rr) * stride + k0 + kk];
            }
        }
        for (int e = tid; e < KC * 16; e += 256) {
            int kk = e / 16, cq = e % 16;
            *(float4*)&Bs[kk * 64 + cq * 4] = *(const float4*)(wc + (size_t)(k0 + kk) * N2 + c0 + cq * 4);
        }
        __syncthreads();
#pragma unroll 8
        for (int kk = 0; kk < KC; kk++) {
            float4 a = *(const float4*)&At[kk * 68 + ty * 4];
            float4 bv = *(const float4*)&Bs[kk * 64 + tx * 4];
            FMA16(a, bv);
        }
    }
    float4 bias = *(const float4*)(b2 + c0 + tx * 4);
#pragma unroll
    for (int ri = 0; ri < 4; ri++) {
        float4 o;
        o.x = acc[ri].x + bias.x; o.y = acc[ri].y + bias.y;
        o.z = acc[ri].z + bias.z; o.w = acc[ri].w + bias.w;
        *(float4*)(pq + (size_t)(r0 + ty * 4 + ri) * N2 + c0 + tx * 4) = o;
    }
}

// ---------------------------------------------------------------- gather + max over 20 neighbors
__global__ void k_gather(const float* __restrict__ pq, const int* __restrict__ idx,
                         float* __restrict__ cat_, int log2dout, int off) {
    int gid = blockIdx.x * 256 + threadIdx.x;
    int dout = 1 << log2dout;
    int row = gid >> log2dout;
    int c = gid & (dout - 1);
    int b = row >> 10;
    int s2 = dout * 2;
    const float* qb = pq + (size_t)(b << 10) * s2 + dout + c;
    const int* ip = idx + (size_t)row * 20;
    float m = -FLT_MAX;
#pragma unroll
    for (int t = 0; t < 20; t++) {
        int j = ip[t];
        m = fmaxf(m, qb[(size_t)j * s2]);
    }
    cat_[(size_t)row * 512 + off + c] = pq[(size_t)row * s2 + c] + m;
}

// ---------------------------------------------------------------- fused linear, 128x128 tile, split 2x2 sub-tiles
// grid (8 col-tiles, 128 row-blocks); stats: colsum/colsq atomics + per (slice,cloud,col) max/min
__global__ __launch_bounds__(256) void k_fused_lin(const float* __restrict__ cat_, const float* __restrict__ Wl,
                                                   const float* __restrict__ bl,
                                                   float* colsum, float* colsq, float* pmax, float* pmin) {
    __shared__ __align__(16) float At[32 * 132];
    __shared__ __align__(16) float Bs[32 * 132];
    __shared__ float red[16 * 128];
    const int tid = threadIdx.x;
    const int tx = tid & 15, ty = tid >> 4;
    const int c0 = blockIdx.x * 128;
    const int rb = blockIdx.y;
    const int r0 = rb * 128;

    float4 a_ll[4] = {}, a_lh[4] = {}, a_hl[4] = {}, a_hh[4] = {};
    for (int kt = 0; kt < 16; kt++) {
        __syncthreads();
        for (int e = tid; e < 128 * 8; e += 256) {
            int rr = e >> 3, kq = e & 7;
            float4 v = *(const float4*)(cat_ + (size_t)(r0 + rr) * 512 + kt * 32 + kq * 4);
            At[(4 * kq + 0) * 132 + rr] = v.x;
            At[(4 * kq + 1) * 132 + rr] = v.y;
            At[(4 * kq + 2) * 132 + rr] = v.z;
            At[(4 * kq + 3) * 132 + rr] = v.w;
        }
        for (int e = tid; e < 32 * 32; e += 256) {
            int kk = e >> 5, cq = e & 31;
            *(float4*)&Bs[kk * 132 + cq * 4] = *(const float4*)(Wl + (size_t)(kt * 32 + kk) * 1024 + c0 + cq * 4);
        }
        __syncthreads();
#pragma unroll 4
        for (int kk = 0; kk < 32; kk++) {
            float4 alo = *(const float4*)&At[kk * 132 + ty * 4];
            float4 ahi = *(const float4*)&At[kk * 132 + 64 + ty * 4];
            float4 blo = *(const float4*)&Bs[kk * 132 + tx * 4];
            float4 bhi = *(const float4*)&Bs[kk * 132 + 64 + tx * 4];
            FMA4(a_ll[0], alo.x, blo); FMA4(a_lh[0], alo.x, bhi);
            FMA4(a_ll[1], alo.y, blo); FMA4(a_lh[1], alo.y, bhi);
            FMA4(a_ll[2], alo.z, blo); FMA4(a_lh[2], alo.z, bhi);
            FMA4(a_ll[3], alo.w, blo); FMA4(a_lh[3], alo.w, bhi);
            FMA4(a_hl[0], ahi.x, blo); FMA4(a_hh[0], ahi.x, bhi);
            FMA4(a_hl[1], ahi.y, blo); FMA4(a_hh[1], ahi.y, bhi);
            FMA4(a_hl[2], ahi.z, blo); FMA4(a_hh[2], ahi.z, bhi);
            FMA4(a_hl[3], ahi.w, blo); FMA4(a_hh[3], ahi.w, bhi);
        }
    }

    float4 bllo = *(const float4*)(bl + c0 + tx * 4);
    float4 blhi = *(const float4*)(bl + c0 + 64 + tx * 4);
    float4 s0 = {0,0,0,0}, s1 = {0,0,0,0}, ss0 = {0,0,0,0}, ss1 = {0,0,0,0};
    float4 mx0 = {-FLT_MAX,-FLT_MAX,-FLT_MAX,-FLT_MAX}, mx1 = mx0;
    float4 mn0 = {FLT_MAX,FLT_MAX,FLT_MAX,FLT_MAX}, mn1 = mn0;
#pragma unroll
    for (int ri = 0; ri < 4; ri++) {
        float4 y;
        // rows ty*4+ri, cols lo
        y.x = a_ll[ri].x + bllo.x; y.y = a_ll[ri].y + bllo.y;
        y.z = a_ll[ri].z + bllo.z; y.w = a_ll[ri].w + bllo.w;
        s0.x += y.x; ss0.x += y.x*y.x; mx0.x = fmaxf(mx0.x, y.x); mn0.x = fminf(mn0.x, y.x);
        s0.y += y.y; ss0.y += y.y*y.y; mx0.y = fmaxf(mx0.y, y.y); mn0.y = fminf(mn0.y, y.y);
        s0.z += y.z; ss0.z += y.z*y.z; mx0.z = fmaxf(mx0.z, y.z); mn0.z = fminf(mn0.z, y.z);
        s0.w += y.w; ss0.w += y.w*y.w; mx0.w = fmaxf(mx0.w, y.w); mn0.w = fminf(mn0.w, y.w);
        // rows 64+ty*4+ri, cols lo
        y.x = a_hl[ri].x + bllo.x; y.y = a_hl[ri].y + bllo.y;
        y.z = a_hl[ri].z + bllo.z; y.w = a_hl[ri].w + bllo.w;
        s0.x += y.x; ss0.x += y.x*y.x; mx0.x = fmaxf(mx0.x, y.x); mn0.x = fminf(mn0.x, y.x);
        s0.y += y.y; ss0.y += y.y*y.y; mx0.y = fmaxf(mx0.y, y.y); mn0.y = fminf(mn0.y, y.y);
        s0.z += y.z; ss0.z += y.z*y.z; mx0.z = fmaxf(mx0.z, y.z); mn0.z = fminf(mn0.z, y.z);
        s0.w += y.w; ss0.w += y.w*y.w; mx0.w = fmaxf(mx0.w, y.w); mn0.w = fminf(mn0.w, y.w);
        // rows ty*4+ri, cols hi
        y.x = a_lh[ri].x + blhi.x; y.y = a_lh[ri].y + blhi.y;
        y.z = a_lh[ri].z + blhi.z; y.w = a_lh[ri].w + blhi.w;
        s1.x += y.x; ss1.x += y.x*y.x; mx1.x = fmaxf(mx1.x, y.x); mn1.x = fminf(mn1.x, y.x);
        s1.y += y.y; ss1.y += y.y*y.y; mx1.y = fmaxf(mx1.y, y.y); mn1.y = fminf(mn1.y, y.y);
        s1.z += y.z; ss1.z += y.z*y.z; mx1.z = fmaxf(mx1.z, y.z); mn1.z = fminf(mn1.z, y.z);
        s1.w += y.w; ss1.w += y.w*y.w; mx1.w = fmaxf(mx1.w, y.w); mn1.w = fminf(mn1.w, y.w);
        // rows 64+ty*4+ri, cols hi
        y.x = a_hh[ri].x + blhi.x; y.y = a_hh[ri].y + blhi.y;
        y.z = a_hh[ri].z + blhi.z; y.w = a_hh[ri].w + blhi.w;
        s1.x += y.x; ss1.x += y.x*y.x; mx1.x = fmaxf(mx1.x, y.x); mn1.x = fminf(mn1.x, y.x);
        s1.y += y.y; ss1.y += y.y*y.y; mx1.y = fmaxf(mx1.y, y.y); mn1.y = fminf(mn1.y, y.y);
        s1.z += y.z; ss1.z += y.z*y.z; mx1.z = fmaxf(mx1.z, y.z); mn1.z = fminf(mn1.z, y.z);
        s1.w += y.w; ss1.w += y.w*y.w; mx1.w = fmaxf(mx1.w, y.w); mn1.w = fminf(mn1.w, y.w);
    }

    float rsum = 0.f, rss = 0.f, rmx = -FLT_MAX, rmn = FLT_MAX;
    __syncthreads();
    *(float4*)&red[ty * 128 + tx * 4] = s0; *(float4*)&red[ty * 128 + 64 + tx * 4] = s1;
    __syncthreads();
    if (tid < 128) for (int t = 0; t < 16; t++) rsum += red[t * 128 + tid];
    __syncthreads();
    *(float4*)&red[ty * 128 + tx * 4] = ss0; *(float4*)&red[ty * 128 + 64 + tx * 4] = ss1;
    __syncthreads();
    if (tid < 128) for (int t = 0; t < 16; t++) rss += red[t * 128 + tid];
    __syncthreads();
    *(float4*)&red[ty * 128 + tx * 4] = mx0; *(float4*)&red[ty * 128 + 64 + tx * 4] = mx1;
    __syncthreads();
    if (tid < 128) for (int t = 0; t < 16; t++) rmx = fmaxf(rmx, red[t * 128 + tid]);
    __syncthreads();
    *(float4*)&red[ty * 128 + tx * 4] = mn0; *(float4*)&red[ty * 128 + 64 + tx * 4] = mn1;
    __syncthreads();
    if (tid < 128) for (int t = 0; t < 16; t++) rmn = fminf(rmn, red[t * 128 + tid]);

    if (tid < 128) {
        int c = c0 + tid;
        int b = rb >> 3, slice = rb & 7;
        atomicAdd(&colsum[c], rsum);
        atomicAdd(&colsq[c], rss);
        pmax[(size_t)(slice * 16 + b) * 1024 + c] = rmx;
        pmin[(size_t)(slice * 16 + b) * 1024 + c] = rmn;
    }
}

// ---------------------------------------------------------------- BN + leaky + pool (commuted through max/min; 8 slices)
__global__ void k_bnpool(const float* colsum, const float* colsq,
                         const float* pmax, const float* pmin,
                         const float* __restrict__ gl, const float* __restrict__ betal,
                         float* __restrict__ pooled) {
    int gid = blockIdx.x * 256 + threadIdx.x;   // 16384
    int c = gid & 1023, b = gid >> 10;
    float mean = colsum[c] * (1.f / 16384.f);
    float var = colsq[c] * (1.f / 16384.f) - mean * mean;
    float a = gl[c] * rsqrtf(var + 1e-5f);
    float d = betal[c] - mean * a;
    float vmx = -FLT_MAX, vmn = FLT_MAX;
#pragma unroll
    for (int rs = 0; rs < 8; rs++) {
        vmx = fmaxf(vmx, pmax[(size_t)(rs * 16 + b) * 1024 + c]);
        vmn = fminf(vmn, pmin[(size_t)(rs * 16 + b) * 1024 + c]);
    }
    float v = a * ((a >= 0.f) ? vmx : vmn) + d;
    pooled[gid] = v > 0.f ? v : 0.2f * v;
}

// ---------------------------------------------------------------- MLP stage 1
__global__ __launch_bounds__(256) void k_mlp1(const float* __restrict__ pooled, const float* __restrict__ Wm1,
                                              const float* __restrict__ bm1, const float* __restrict__ gm1,
                                              const float* __restrict__ betam1, float* __restrict__ hbuf) {
    int tid = threadIdx.x;
    int r = tid >> 4, cl = tid & 15;
    int c = blockIdx.x * 16 + cl;
    float z = bm1[c];
    const float* pr = pooled + (size_t)r * 1024;
    for (int kk = 0; kk < 1024; kk++) z += pr[kk] * Wm1[(size_t)kk * 512 + c];
    __shared__ float zb[16 * 16];
    zb[r * 16 + cl] = z;
    __syncthreads();
    float sm = 0.f, sq = 0.f;
#pragma unroll
    for (int rr = 0; rr < 16; rr++) { float v = zb[rr * 16 + cl]; sm += v; sq += v * v; }
    float mean = sm * (1.f / 16.f);
    float var = sq * (1.f / 16.f) - mean * mean;
    float h = gm1[c] * (z - mean) * rsqrtf(var + 1e-5f) + betam1[c];
    hbuf[(size_t)r * 512 + c] = h > 0.f ? h : 0.2f * h;
}

// ---------------------------------------------------------------- MLP stage 2
__global__ void k_mlp2(const float* __restrict__ hbuf, const float* __restrict__ Wm2,
                       const float* __restrict__ bm2, float* __restrict__ out) {
    int gid = blockIdx.x * 256 + threadIdx.x;
    if (gid >= 640) return;
    int r = gid / 40, c = gid % 40;
    float o = bm2[c];
    const float* hr = hbuf + (size_t)r * 512;
    for (int kk = 0; kk < 512; kk++) o += hr[kk] * Wm2[(size_t)kk * 40 + c];
    out[gid] = o;
}

// ----------------------------------------------------------------
extern "C" void kernel_launch(void* const* d_in, const int* in_sizes, int n_in,
                              void* d_out, int out_size, void* d_ws, size_t ws_size,
                              hipStream_t stream) {
    const float* pos = (const float*)d_in[0];
    const float* W1 = (const float*)d_in[2];
    const float* b1 = (const float*)d_in[3];
    const float* W2 = (const float*)d_in[4];
    const float* b2 = (const float*)d_in[5];
    const float* W3 = (const float*)d_in[6];
    const float* b3 = (const float*)d_in[7];
    const float* W4 = (const float*)d_in[8];
    const float* b4 = (const float*)d_in[9];
    const float* Wl = (const float*)d_in[10];
    const float* bl = (const float*)d_in[11];
    const float* gl = (const float*)d_in[12];
    const float* betal = (const float*)d_in[13];
    const float* Wm1 = (const float*)d_in[14];
    const float* bm1 = (const float*)d_in[15];
    const float* gm1 = (const float*)d_in[16];
    const float* betam1 = (const float*)d_in[17];
    const float* Wm2 = (const float*)d_in[18];
    const float* bm2 = (const float*)d_in[19];
    float* out = (float*)d_out;

    float* ws = (float*)d_ws;
    float* cat_ = ws;                                   // 16384*512
    float* pq = cat_ + (size_t)NROW * 512;              // 16384*512 (aliased by dist, then pmax/pmin)
    int* idx = (int*)(pq + (size_t)NROW * 512);         // 16384*20
    float* sqb = (float*)(idx + NROW * 20);             // 16384
    float* wc1 = sqb + NROW;
    float* wc2 = wc1 + 3 * 128;
    float* wc3 = wc2 + 64 * 128;
    float* wc4 = wc3 + 64 * 256;
    float* bb1 = wc4 + 128 * 512;
    float* bb2 = bb1 + 128;
    float* bb3 = bb2 + 128;
    float* bb4 = bb3 + 256;
    float* colsum = bb4 + 512;
    float* colsq = colsum + 1024;
    float* pooled = colsq + 1024;                       // 16384
    float* hbuf = pooled + NROW;                        // 8192
    size_t need = (size_t)((hbuf + 16 * 512) - ws) * sizeof(float);
    if (ws_size < need) return;

    float* dist = pq;                 // 8*1024*1024 floats; dead after select
    float* pmax = pq;                 // 8*16*1024, alias pq after final gather
    float* pmin = pq + 8 * 16 * 1024;

    k_prep<<<256, 256, 0, stream>>>(W1, b1, wc1, bb1, 3, 64);
    k_prep<<<256, 256, 0, stream>>>(W2, b2, wc2, bb2, 64, 64);
    k_prep<<<256, 256, 0, stream>>>(W3, b3, wc3, bb3, 64, 128);
    k_prep<<<256, 256, 0, stream>>>(W4, b4, wc4, bb4, 128, 256);

    // layer 1 (D=3 -> 64)
    k_sqnorm<<<4096, 256, 0, stream>>>(pos, 3, 3, sqb);
    for (int p = 0; p < 2; p++) {
        k_dist<3><<<dim3(8, 8, 8), 256, 0, stream>>>(pos, 3, sqb, dist, p);
        k_select<<<2048, 256, 0, stream>>>(dist, idx, p);
    }
    k_gemm_pq<3, 64><<<dim3(256, 2), 256, 0, stream>>>(pos, 3, wc1, bb1, pq);
    k_gather<<<4096, 256, 0, stream>>>(pq, idx, cat_, 6, 0);
    // layer 2 (64 -> 64)
    k_sqnorm<<<4096, 256, 0, stream>>>(cat_, 512, 64, sqb);
    for (int p = 0; p < 2; p++) {
        k_dist<64><<<dim3(8, 8, 8), 256, 0, stream>>>(cat_, 512, sqb, dist, p);
        k_select<<<2048, 256, 0, stream>>>(dist, idx, p);
    }
    k_gemm_pq<64, 64><<<dim3(256, 2), 256, 0, stream>>>(cat_, 512, wc2, bb2, pq);
    k_gather<<<4096, 256, 0, stream>>>(pq, idx, cat_, 6, 64);
    // layer 3 (64 -> 128)
    k_sqnorm<<<4096, 256, 0, stream>>>(cat_ + 64, 512, 64, sqb);
    for (int p = 0; p < 2; p++) {
        k_dist<64><<<dim3(8, 8, 8), 256, 0, stream>>>(cat_ + 64, 512, sqb, dist, p);
        k_select<<<2048, 256, 0, stream>>>(dist, idx, p);
    }
    k_gemm_pq<64, 128><<<dim3(256, 4), 256, 0, stream>>>(cat_ + 64, 512, wc3, bb3, pq);
    k_gather<<<8192, 256, 0, stream>>>(pq, idx, cat_, 7, 128);
    // layer 4 (128 -> 256)
    k_sqnorm<<<4096, 256, 0, stream>>>(cat_ + 128, 512, 128, sqb);
    for (int p = 0; p < 2; p++) {
        k_dist<128><<<dim3(8, 8, 8), 256, 0, stream>>>(cat_ + 128, 512, sqb, dist, p);
        k_select<<<2048, 256, 0, stream>>>(dist, idx, p);
    }
    k_gemm_pq<128, 256><<<dim3(256, 8), 256, 0, stream>>>(cat_ + 128, 512, wc4, bb4, pq);
    k_gather<<<16384, 256, 0, stream>>>(pq, idx, cat_, 8, 256);

    // pq now dead; pmax/pmin alias it
    k_init<<<512, 256, 0, stream>>>(colsum, colsq, pmax, pmin);
    k_fused_lin<<<dim3(8, 128), 256, 0, stream>>>(cat_, Wl, bl, colsum, colsq, pmax, pmin);
    k_bnpool<<<64, 256, 0, stream>>>(colsum, colsq, pmax, pmin, gl, betal, pooled);
    k_mlp1<<<32, 256, 0, stream>>>(pooled, Wm1, bm1, gm1, betam1, hbuf);
    k_mlp2<<<3, 256, 0, stream>>>(hbuf, Wm2, bm2, out);
}

// Round 15
// 958.973 us; speedup vs baseline: 1.0122x; 1.0122x over previous
//
#include <hip/hip_runtime.h>
#include <float.h>

#define NB 16
#define NP 1024
#define NROW (NB*NP)

// ---------------------------------------------------------------- init (stats+pool buffers; pmax/pmin alias pq, init AFTER gather L4)
__global__ void k_init(float* colsum, float* colsq, float* pmax, float* pmin) {
    int i = blockIdx.x * 256 + threadIdx.x;          // grid 512 -> i < 131072
    if (i < 1024) { colsum[i] = 0.f; colsq[i] = 0.f; }
    pmax[i] = -FLT_MAX;
    pmin[i] =  FLT_MAX;
}

// ---------------------------------------------------------------- weight prep
__global__ void k_prep(const float* __restrict__ W, const float* __restrict__ b,
                       float* __restrict__ wc, float* __restrict__ b2, int d, int dout) {
    int n2 = 2 * dout;
    int i = blockIdx.x * 256 + threadIdx.x;
    if (i < d * n2) {
        int kk = i / n2, c = i % n2;
        wc[i] = (c < dout) ? (W[kk * dout + c] - W[(kk + d) * dout + c])
                           : W[(kk + d) * dout + (c - dout)];
    }
    if (i < n2) b2[i] = (i < dout) ? b[i] : 0.f;
}

// ---------------------------------------------------------------- squared norms
__global__ void k_sqnorm(const float* __restrict__ x, int stride, int D, float* __restrict__ sq) {
    int row = blockIdx.x * 4 + (threadIdx.x >> 6);
    int lane = threadIdx.x & 63;
    const float* xr = x + (size_t)row * stride;
    float s = 0.f;
    for (int kk = lane; kk < D; kk += 64) { float v = xr[kk]; s += v * v; }
    for (int o = 32; o; o >>= 1) s += __shfl_down(s, o);
    if (lane == 0) sq[row] = s;
}

// ---------------------------------------------------------------- float -> order-preserving u32
__device__ inline unsigned ford(float f) {
    unsigned u = __float_as_uint(f);
    return (u & 0x80000000u) ? ~u : (u | 0x80000000u);
}

// 4 FMAs: c (float4) += s * b
#define FMA4(c_, s_, b_) do { \
    (c_).x += (s_)*(b_).x; (c_).y += (s_)*(b_).y; (c_).z += (s_)*(b_).z; (c_).w += (s_)*(b_).w; \
} while (0)

#define FMA16(a, bv) do { \
    acc[0].x += (a).x*(bv).x; acc[0].y += (a).x*(bv).y; acc[0].z += (a).x*(bv).z; acc[0].w += (a).x*(bv).w; \
    acc[1].x += (a).y*(bv).x; acc[1].y += (a).y*(bv).y; acc[1].z += (a).y*(bv).z; acc[1].w += (a).y*(bv).w; \
    acc[2].x += (a).z*(bv).x; acc[2].y += (a).z*(bv).y; acc[2].z += (a).z*(bv).z; acc[2].w += (a).z*(bv).w; \
    acc[3].x += (a).w*(bv).x; acc[3].y += (a).w*(bv).y; acc[3].z += (a).w*(bv).z; acc[3].w += (a).w*(bv).w; \
} while (0)

// ---------------------------------------------------------------- distance tile GEMM, 128x128 tile, split 2x2 sub-tiles (4+4)
// dist[r][j] = sq[j] - 2 * x_r . x_j ; grid (8 j-tiles, 8 row-tiles, 8 clouds), block 256.
template<int D>
__global__ __launch_bounds__(256) void k_dist(const float* __restrict__ x, int stride,
                                              const float* __restrict__ sq,
                                              float* __restrict__ dist, int pass) {
    constexpr int KC = (D < 32) ? D : 32;
    __shared__ __align__(16) float At[KC * 132];
    __shared__ __align__(16) float Bt[KC * 132];
    const int tid = threadIdx.x;
    const int tx = tid & 15, ty = tid >> 4;
    const int j0 = blockIdx.x * 128;
    const int r0 = blockIdx.y * 128;
    const int bb = pass * 8 + blockIdx.z;

    float4 a_ll[4] = {}, a_lh[4] = {}, a_hl[4] = {}, a_hh[4] = {};
    for (int k0 = 0; k0 < D; k0 += KC) {
        __syncthreads();
        if constexpr (KC % 4 == 0) {
            constexpr int K4 = KC / 4;
            for (int e = tid; e < 128 * K4; e += 256) {
                int rr = e / K4, kq = e % K4;
                float4 v = *(const float4*)(x + (size_t)(bb * NP + r0 + rr) * stride + k0 + kq * 4);
                At[(4 * kq + 0) * 132 + rr] = v.x;
                At[(4 * kq + 1) * 132 + rr] = v.y;
                At[(4 * kq + 2) * 132 + rr] = v.z;
                At[(4 * kq + 3) * 132 + rr] = v.w;
            }
            for (int e = tid; e < 128 * K4; e += 256) {
                int jj = e / K4, kq = e % K4;
                float4 v = *(const float4*)(x + (size_t)(bb * NP + j0 + jj) * stride + k0 + kq * 4);
                Bt[(4 * kq + 0) * 132 + jj] = v.x;
                Bt[(4 * kq + 1) * 132 + jj] = v.y;
                Bt[(4 * kq + 2) * 132 + jj] = v.z;
                Bt[(4 * kq + 3) * 132 + jj] = v.w;
            }
        } else {
            for (int e = tid; e < 128 * KC; e += 256) {
                int rr = e / KC, kk = e % KC;
                At[kk * 132 + rr] = x[(size_t)(bb * NP + r0 + rr) * stride + k0 + kk];
            }
            for (int e = tid; e < 128 * KC; e += 256) {
                int jj = e / KC, kk = e % KC;
                Bt[kk * 132 + jj] = x[(size_t)(bb * NP + j0 + jj) * stride + k0 + kk];
            }
        }
        __syncthreads();
#pragma unroll 4
        for (int kk = 0; kk < KC; kk++) {
            float4 alo = *(const float4*)&At[kk * 132 + ty * 4];
            float4 ahi = *(const float4*)&At[kk * 132 + 64 + ty * 4];
            float4 blo = *(const float4*)&Bt[kk * 132 + tx * 4];
            float4 bhi = *(const float4*)&Bt[kk * 132 + 64 + tx * 4];
            FMA4(a_ll[0], alo.x, blo); FMA4(a_lh[0], alo.x, bhi);
            FMA4(a_ll[1], alo.y, blo); FMA4(a_lh[1], alo.y, bhi);
            FMA4(a_ll[2], alo.z, blo); FMA4(a_lh[2], alo.z, bhi);
            FMA4(a_ll[3], alo.w, blo); FMA4(a_lh[3], alo.w, bhi);
            FMA4(a_hl[0], ahi.x, blo); FMA4(a_hh[0], ahi.x, bhi);
            FMA4(a_hl[1], ahi.y, blo); FMA4(a_hh[1], ahi.y, bhi);
            FMA4(a_hl[2], ahi.z, blo); FMA4(a_hh[2], ahi.z, bhi);
            FMA4(a_hl[3], ahi.w, blo); FMA4(a_hh[3], ahi.w, bhi);
        }
    }
    float4 sqlo = *(const float4*)(sq + bb * NP + j0 + tx * 4);
    float4 sqhi = *(const float4*)(sq + bb * NP + j0 + 64 + tx * 4);
#pragma unroll
    for (int ri = 0; ri < 4; ri++) {
        float* dlo = dist + (size_t)(blockIdx.z * NP + r0 + ty * 4 + ri) * NP + j0;
        float* dhi = dist + (size_t)(blockIdx.z * NP + r0 + 64 + ty * 4 + ri) * NP + j0;
        float4 o;
        o.x = sqlo.x - 2.f * a_ll[ri].x; o.y = sqlo.y - 2.f * a_ll[ri].y;
        o.z = sqlo.z - 2.f * a_ll[ri].z; o.w = sqlo.w - 2.f * a_ll[ri].w;
        *(float4*)(dlo + tx * 4) = o;
        o.x = sqhi.x - 2.f * a_lh[ri].x; o.y = sqhi.y - 2.f * a_lh[ri].y;
        o.z = sqhi.z - 2.f * a_lh[ri].z; o.w = sqhi.w - 2.f * a_lh[ri].w;
        *(float4*)(dlo + 64 + tx * 4) = o;
        o.x = sqlo.x - 2.f * a_hl[ri].x; o.y = sqlo.y - 2.f * a_hl[ri].y;
        o.z = sqlo.z - 2.f * a_hl[ri].z; o.w = sqlo.w - 2.f * a_hl[ri].w;
        *(float4*)(dhi + tx * 4) = o;
        o.x = sqhi.x - 2.f * a_hh[ri].x; o.y = sqhi.y - 2.f * a_hh[ri].y;
        o.z = sqhi.z - 2.f * a_hh[ri].z; o.w = sqhi.w - 2.f * a_hh[ri].w;
        *(float4*)(dhi + 64 + tx * 4) = o;
    }
}

// ---------------------------------------------------------------- top-20 select: one wave per row
__global__ __launch_bounds__(256) void k_select(const float* __restrict__ dist,
                                                int* __restrict__ idxout, int pass) {
    const int w = threadIdx.x >> 6, lane = threadIdx.x & 63;
    const int rowlocal = blockIdx.x * 4 + w;          // 0..8191 per pass
    const size_t base = (size_t)rowlocal * NP;
    const int growrow = pass * 8 * NP + rowlocal;

    unsigned long long pk[16];
    const float4* dp = (const float4*)(dist + base + lane * 16);
#pragma unroll
    for (int q = 0; q < 4; q++) {
        float4 v = dp[q];
        int jb = lane * 16 + q * 4;
        pk[q * 4 + 0] = ((unsigned long long)ford(v.x) << 32) | (unsigned)(jb + 0);
        pk[q * 4 + 1] = ((unsigned long long)ford(v.y) << 32) | (unsigned)(jb + 1);
        pk[q * 4 + 2] = ((unsigned long long)ford(v.z) << 32) | (unsigned)(jb + 2);
        pk[q * 4 + 3] = ((unsigned long long)ford(v.w) << 32) | (unsigned)(jb + 3);
    }
    unsigned msk = 0;
#pragma unroll 1
    for (int it = 0; it < 20; it++) {
        unsigned long long m = 0xFFFFFFFFFFFFFFFFULL;
#pragma unroll
        for (int t = 0; t < 16; t++) {
            unsigned long long v = (msk & (1u << t)) ? 0xFFFFFFFFFFFFFFFFULL : pk[t];
            m = (v < m) ? v : m;
        }
#pragma unroll
        for (int o = 32; o; o >>= 1) {
            unsigned long long v = __shfl_xor(m, o);
            m = (v < m) ? v : m;
        }
        unsigned wj = (unsigned)(m & 0xFFFFFFFFu);
        if (lane == (int)(wj >> 4)) msk |= 1u << (wj & 15u);
        if (lane == 0) idxout[(size_t)growrow * 20 + it] = (int)wj;
    }
}

// ---------------------------------------------------------------- p/q GEMM (64-tile 4x4; small, unchanged)
template<int D, int DOUT>
__global__ __launch_bounds__(256) void k_gemm_pq(const float* __restrict__ x, int stride,
                                                 const float* __restrict__ wc, const float* __restrict__ b2,
                                                 float* __restrict__ pq) {
    constexpr int N2 = 2 * DOUT;
    constexpr int KC = (D > 64) ? 64 : D;
    __shared__ __align__(16) float At[KC * 68];
    __shared__ __align__(16) float Bs[KC * 64];
    const int tid = threadIdx.x;
    const int tx = tid & 15, ty = tid >> 4;
    const int r0 = blockIdx.x * 64;
    const int c0 = blockIdx.y * 64;

    float4 acc[4] = {};
    for (int k0 = 0; k0 < D; k0 += KC) {
        __syncthreads();
        if constexpr (KC % 4 == 0) {
            constexpr int K4 = KC / 4;
            for (int e = tid; e < 64 * K4; e += 256) {
                int rr = e / K4, kq = e % K4;
                float4 v = *(const float4*)(x + (size_t)(r0 + rr) * stride + k0 + kq * 4);
                At[(4 * kq + 0) * 68 + rr] = v.x;
                At[(4 * kq + 1) * 68 + rr] = v.y;
                At[(4 * kq + 2) * 68 + rr] = v.z;
                At[(4 * kq + 3) * 68 + rr] = v.w;
            }
        } else {
            for (int e = tid; e < 64 * KC; e += 256) {
                int rr = e / KC, kk = e % KC;
                At[kk * 68 + rr] = x[(size_t)(r0 + rr) * stride + k0 + kk];
            }
        }
        for (int e = tid; e < KC * 16; e += 256) {
            int kk = e / 16, cq = e % 16;
            *(float4*)&Bs[kk * 64 + cq * 4] = *(const float4*)(wc + (size_t)(k0 + kk) * N2 + c0 + cq * 4);
        }
        __syncthreads();
#pragma unroll 8
        for (int kk = 0; kk < KC; kk++) {
            float4 a = *(const float4*)&At[kk * 68 + ty * 4];
            float4 bv = *(const float4*)&Bs[kk * 64 + tx * 4];
            FMA16(a, bv);
        }
    }
    float4 bias = *(const float4*)(b2 + c0 + tx * 4);
#pragma unroll
    for (int ri = 0; ri < 4; ri++) {
        float4 o;
        o.x = acc[ri].x + bias.x; o.y = acc[ri].y + bias.y;
        o.z = acc[ri].z + bias.z; o.w = acc[ri].w + bias.w;
        *(float4*)(pq + (size_t)(r0 + ty * 4 + ri) * N2 + c0 + tx * 4) = o;
    }
}

// ---------------------------------------------------------------- gather + max over 20 neighbors
__global__ void k_gather(const float* __restrict__ pq, const int* __restrict__ idx,
                         float* __restrict__ cat_, int log2dout, int off) {
    int gid = blockIdx.x * 256 + threadIdx.x;
    int dout = 1 << log2dout;
    int row = gid >> log2dout;
    int c = gid & (dout - 1);
    int b = row >> 10;
    int s2 = dout * 2;
    const float* qb = pq + (size_t)(b << 10) * s2 + dout + c;
    const int* ip = idx + (size_t)row * 20;
    float m = -FLT_MAX;
#pragma unroll
    for (int t = 0; t < 20; t++) {
        int j = ip[t];
        m = fmaxf(m, qb[(size_t)j * s2]);
    }
    cat_[(size_t)row * 512 + off + c] = pq[(size_t)row * s2 + c] + m;
}

// ---------------------------------------------------------------- fused linear, 128x128 tile, split 2x2 sub-tiles
// LDS: red UNIONED with At (red only used after kt loop) -> 33.8KB -> 4 blocks/CU
__global__ __launch_bounds__(256) void k_fused_lin(const float* __restrict__ cat_, const float* __restrict__ Wl,
                                                   const float* __restrict__ bl,
                                                   float* colsum, float* colsq, float* pmax, float* pmin) {
    __shared__ __align__(16) float smem[2 * 32 * 132];
    float* At = smem;
    float* Bs = smem + 32 * 132;
    float* red = smem;                 // alias At: only touched after compute loop + barrier
    const int tid = threadIdx.x;
    const int tx = tid & 15, ty = tid >> 4;
    const int c0 = blockIdx.x * 128;
    const int rb = blockIdx.y;
    const int r0 = rb * 128;

    float4 a_ll[4] = {}, a_lh[4] = {}, a_hl[4] = {}, a_hh[4] = {};
    for (int kt = 0; kt < 16; kt++) {
        __syncthreads();
        for (int e = tid; e < 128 * 8; e += 256) {
            int rr = e >> 3, kq = e & 7;
            float4 v = *(const float4*)(cat_ + (size_t)(r0 + rr) * 512 + kt * 32 + kq * 4);
            At[(4 * kq + 0) * 132 + rr] = v.x;
            At[(4 * kq + 1) * 132 + rr] = v.y;
            At[(4 * kq + 2) * 132 + rr] = v.z;
            At[(4 * kq + 3) * 132 + rr] = v.w;
        }
        for (int e = tid; e < 32 * 32; e += 256) {
            int kk = e >> 5, cq = e & 31;
            *(float4*)&Bs[kk * 132 + cq * 4] = *(const float4*)(Wl + (size_t)(kt * 32 + kk) * 1024 + c0 + cq * 4);
        }
        __syncthreads();
#pragma unroll 4
        for (int kk = 0; kk < 32; kk++) {
            float4 alo = *(const float4*)&At[kk * 132 + ty * 4];
            float4 ahi = *(const float4*)&At[kk * 132 + 64 + ty * 4];
            float4 blo = *(const float4*)&Bs[kk * 132 + tx * 4];
            float4 bhi = *(const float4*)&Bs[kk * 132 + 64 + tx * 4];
            FMA4(a_ll[0], alo.x, blo); FMA4(a_lh[0], alo.x, bhi);
            FMA4(a_ll[1], alo.y, blo); FMA4(a_lh[1], alo.y, bhi);
            FMA4(a_ll[2], alo.z, blo); FMA4(a_lh[2], alo.z, bhi);
            FMA4(a_ll[3], alo.w, blo); FMA4(a_lh[3], alo.w, bhi);
            FMA4(a_hl[0], ahi.x, blo); FMA4(a_hh[0], ahi.x, bhi);
            FMA4(a_hl[1], ahi.y, blo); FMA4(a_hh[1], ahi.y, bhi);
            FMA4(a_hl[2], ahi.z, blo); FMA4(a_hh[2], ahi.z, bhi);
            FMA4(a_hl[3], ahi.w, blo); FMA4(a_hh[3], ahi.w, bhi);
        }
    }

    float4 bllo = *(const float4*)(bl + c0 + tx * 4);
    float4 blhi = *(const float4*)(bl + c0 + 64 + tx * 4);
    float4 s0 = {0,0,0,0}, s1 = {0,0,0,0}, ss0 = {0,0,0,0}, ss1 = {0,0,0,0};
    float4 mx0 = {-FLT_MAX,-FLT_MAX,-FLT_MAX,-FLT_MAX}, mx1 = mx0;
    float4 mn0 = {FLT_MAX,FLT_MAX,FLT_MAX,FLT_MAX}, mn1 = mn0;
#pragma unroll
    for (int ri = 0; ri < 4; ri++) {
        float4 y;
        y.x = a_ll[ri].x + bllo.x; y.y = a_ll[ri].y + bllo.y;
        y.z = a_ll[ri].z + bllo.z; y.w = a_ll[ri].w + bllo.w;
        s0.x += y.x; ss0.x += y.x*y.x; mx0.x = fmaxf(mx0.x, y.x); mn0.x = fminf(mn0.x, y.x);
        s0.y += y.y; ss0.y += y.y*y.y; mx0.y = fmaxf(mx0.y, y.y); mn0.y = fminf(mn0.y, y.y);
        s0.z += y.z; ss0.z += y.z*y.z; mx0.z = fmaxf(mx0.z, y.z); mn0.z = fminf(mn0.z, y.z);
        s0.w += y.w; ss0.w += y.w*y.w; mx0.w = fmaxf(mx0.w, y.w); mn0.w = fminf(mn0.w, y.w);
        y.x = a_hl[ri].x + bllo.x; y.y = a_hl[ri].y + bllo.y;
        y.z = a_hl[ri].z + bllo.z; y.w = a_hl[ri].w + bllo.w;
        s0.x += y.x; ss0.x += y.x*y.x; mx0.x = fmaxf(mx0.x, y.x); mn0.x = fminf(mn0.x, y.x);
        s0.y += y.y; ss0.y += y.y*y.y; mx0.y = fmaxf(mx0.y, y.y); mn0.y = fminf(mn0.y, y.y);
        s0.z += y.z; ss0.z += y.z*y.z; mx0.z = fmaxf(mx0.z, y.z); mn0.z = fminf(mn0.z, y.z);
        s0.w += y.w; ss0.w += y.w*y.w; mx0.w = fmaxf(mx0.w, y.w); mn0.w = fminf(mn0.w, y.w);
        y.x = a_lh[ri].x + blhi.x; y.y = a_lh[ri].y + blhi.y;
        y.z = a_lh[ri].z + blhi.z; y.w = a_lh[ri].w + blhi.w;
        s1.x += y.x; ss1.x += y.x*y.x; mx1.x = fmaxf(mx1.x, y.x); mn1.x = fminf(mn1.x, y.x);
        s1.y += y.y; ss1.y += y.y*y.y; mx1.y = fmaxf(mx1.y, y.y); mn1.y = fminf(mn1.y, y.y);
        s1.z += y.z; ss1.z += y.z*y.z; mx1.z = fmaxf(mx1.z, y.z); mn1.z = fminf(mn1.z, y.z);
        s1.w += y.w; ss1.w += y.w*y.w; mx1.w = fmaxf(mx1.w, y.w); mn1.w = fminf(mn1.w, y.w);
        y.x = a_hh[ri].x + blhi.x; y.y = a_hh[ri].y + blhi.y;
        y.z = a_hh[ri].z + blhi.z; y.w = a_hh[ri].w + blhi.w;
        s1.x += y.x; ss1.x += y.x*y.x; mx1.x = fmaxf(mx1.x, y.x); mn1.x = fminf(mn1.x, y.x);
        s1.y += y.y; ss1.y += y.y*y.y; mx1.y = fmaxf(mx1.y, y.y); mn1.y = fminf(mn1.y, y.y);
        s1.z += y.z; ss1.z += y.z*y.z; mx1.z = fmaxf(mx1.z, y.z); mn1.z = fminf(mn1.z, y.z);
        s1.w += y.w; ss1.w += y.w*y.w; mx1.w = fmaxf(mx1.w, y.w); mn1.w = fminf(mn1.w, y.w);
    }

    float rsum = 0.f, rss = 0.f, rmx = -FLT_MAX, rmn = FLT_MAX;
    __syncthreads();   // compute done everywhere; safe to overwrite At via red
    *(float4*)&red[ty * 128 + tx * 4] = s0; *(float4*)&red[ty * 128 + 64 + tx * 4] = s1;
    __syncthreads();
    if (tid < 128) for (int t = 0; t < 16; t++) rsum += red[t * 128 + tid];
    __syncthreads();
    *(float4*)&red[ty * 128 + tx * 4] = ss0; *(float4*)&red[ty * 128 + 64 + tx * 4] = ss1;
    __syncthreads();
    if (tid < 128) for (int t = 0; t < 16; t++) rss += red[t * 128 + tid];
    __syncthreads();
    *(float4*)&red[ty * 128 + tx * 4] = mx0; *(float4*)&red[ty * 128 + 64 + tx * 4] = mx1;
    __syncthreads();
    if (tid < 128) for (int t = 0; t < 16; t++) rmx = fmaxf(rmx, red[t * 128 + tid]);
    __syncthreads();
    *(float4*)&red[ty * 128 + tx * 4] = mn0; *(float4*)&red[ty * 128 + 64 + tx * 4] = mn1;
    __syncthreads();
    if (tid < 128) for (int t = 0; t < 16; t++) rmn = fminf(rmn, red[t * 128 + tid]);

    if (tid < 128) {
        int c = c0 + tid;
        int b = rb >> 3, slice = rb & 7;
        atomicAdd(&colsum[c], rsum);
        atomicAdd(&colsq[c], rss);
        pmax[(size_t)(slice * 16 + b) * 1024 + c] = rmx;
        pmin[(size_t)(slice * 16 + b) * 1024 + c] = rmn;
    }
}

// ---------------------------------------------------------------- BN + leaky + pool (commuted through max/min; 8 slices)
__global__ void k_bnpool(const float* colsum, const float* colsq,
                         const float* pmax, const float* pmin,
                         const float* __restrict__ gl, const float* __restrict__ betal,
                         float* __restrict__ pooled) {
    int gid = blockIdx.x * 256 + threadIdx.x;   // 16384
    int c = gid & 1023, b = gid >> 10;
    float mean = colsum[c] * (1.f / 16384.f);
    float var = colsq[c] * (1.f / 16384.f) - mean * mean;
    float a = gl[c] * rsqrtf(var + 1e-5f);
    float d = betal[c] - mean * a;
    float vmx = -FLT_MAX, vmn = FLT_MAX;
#pragma unroll
    for (int rs = 0; rs < 8; rs++) {
        vmx = fmaxf(vmx, pmax[(size_t)(rs * 16 + b) * 1024 + c]);
        vmn = fminf(vmn, pmin[(size_t)(rs * 16 + b) * 1024 + c]);
    }
    float v = a * ((a >= 0.f) ? vmx : vmn) + d;
    pooled[gid] = v > 0.f ? v : 0.2f * v;
}

// ---------------------------------------------------------------- MLP stage 1
__global__ __launch_bounds__(256) void k_mlp1(const float* __restrict__ pooled, const float* __restrict__ Wm1,
                                              const float* __restrict__ bm1, const float* __restrict__ gm1,
                                              const float* __restrict__ betam1, float* __restrict__ hbuf) {
    int tid = threadIdx.x;
    int r = tid >> 4, cl = tid & 15;
    int c = blockIdx.x * 16 + cl;
    float z = bm1[c];
    const float* pr = pooled + (size_t)r * 1024;
    for (int kk = 0; kk < 1024; kk++) z += pr[kk] * Wm1[(size_t)kk * 512 + c];
    __shared__ float zb[16 * 16];
    zb[r * 16 + cl] = z;
    __syncthreads();
    float sm = 0.f, sq = 0.f;
#pragma unroll
    for (int rr = 0; rr < 16; rr++) { float v = zb[rr * 16 + cl]; sm += v; sq += v * v; }
    float mean = sm * (1.f / 16.f);
    float var = sq * (1.f / 16.f) - mean * mean;
    float h = gm1[c] * (z - mean) * rsqrtf(var + 1e-5f) + betam1[c];
    hbuf[(size_t)r * 512 + c] = h > 0.f ? h : 0.2f * h;
}

// ---------------------------------------------------------------- MLP stage 2
__global__ void k_mlp2(const float* __restrict__ hbuf, const float* __restrict__ Wm2,
                       const float* __restrict__ bm2, float* __restrict__ out) {
    int gid = blockIdx.x * 256 + threadIdx.x;
    if (gid >= 640) return;
    int r = gid / 40, c = gid % 40;
    float o = bm2[c];
    const float* hr = hbuf + (size_t)r * 512;
    for (int kk = 0; kk < 512; kk++) o += hr[kk] * Wm2[(size_t)kk * 40 + c];
    out[gid] = o;
}

// ----------------------------------------------------------------
extern "C" void kernel_launch(void* const* d_in, const int* in_sizes, int n_in,
                              void* d_out, int out_size, void* d_ws, size_t ws_size,
                              hipStream_t stream) {
    const float* pos = (const float*)d_in[0];
    const float* W1 = (const float*)d_in[2];
    const float* b1 = (const float*)d_in[3];
    const float* W2 = (const float*)d_in[4];
    const float* b2 = (const float*)d_in[5];
    const float* W3 = (const float*)d_in[6];
    const float* b3 = (const float*)d_in[7];
    const float* W4 = (const float*)d_in[8];
    const float* b4 = (const float*)d_in[9];
    const float* Wl = (const float*)d_in[10];
    const float* bl = (const float*)d_in[11];
    const float* gl = (const float*)d_in[12];
    const float* betal = (const float*)d_in[13];
    const float* Wm1 = (const float*)d_in[14];
    const float* bm1 = (const float*)d_in[15];
    const float* gm1 = (const float*)d_in[16];
    const float* betam1 = (const float*)d_in[17];
    const float* Wm2 = (const float*)d_in[18];
    const float* bm2 = (const float*)d_in[19];
    float* out = (float*)d_out;

    float* ws = (float*)d_ws;
    float* cat_ = ws;                                   // 16384*512
    float* pq = cat_ + (size_t)NROW * 512;              // 16384*512 (aliased by dist, then pmax/pmin)
    int* idx = (int*)(pq + (size_t)NROW * 512);         // 16384*20
    float* sqb = (float*)(idx + NROW * 20);             // 16384
    float* wc1 = sqb + NROW;
    float* wc2 = wc1 + 3 * 128;
    float* wc3 = wc2 + 64 * 128;
    float* wc4 = wc3 + 64 * 256;
    float* bb1 = wc4 + 128 * 512;
    float* bb2 = bb1 + 128;
    float* bb3 = bb2 + 128;
    float* bb4 = bb3 + 256;
    float* colsum = bb4 + 512;
    float* colsq = colsum + 1024;
    float* pooled = colsq + 1024;                       // 16384
    float* hbuf = pooled + NROW;                        // 8192
    size_t need = (size_t)((hbuf + 16 * 512) - ws) * sizeof(float);
    if (ws_size < need) return;

    float* dist = pq;                 // 8*1024*1024 floats; dead after select
    float* pmax = pq;                 // 8*16*1024, alias pq after final gather
    float* pmin = pq + 8 * 16 * 1024;

    k_prep<<<256, 256, 0, stream>>>(W1, b1, wc1, bb1, 3, 64);
    k_prep<<<256, 256, 0, stream>>>(W2, b2, wc2, bb2, 64, 64);
    k_prep<<<256, 256, 0, stream>>>(W3, b3, wc3, bb3, 64, 128);
    k_prep<<<256, 256, 0, stream>>>(W4, b4, wc4, bb4, 128, 256);

    // layer 1 (D=3 -> 64)
    k_sqnorm<<<4096, 256, 0, stream>>>(pos, 3, 3, sqb);
    for (int p = 0; p < 2; p++) {
        k_dist<3><<<dim3(8, 8, 8), 256, 0, stream>>>(pos, 3, sqb, dist, p);
        k_select<<<2048, 256, 0, stream>>>(dist, idx, p);
    }
    k_gemm_pq<3, 64><<<dim3(256, 2), 256, 0, stream>>>(pos, 3, wc1, bb1, pq);
    k_gather<<<4096, 256, 0, stream>>>(pq, idx, cat_, 6, 0);
    // layer 2 (64 -> 64)
    k_sqnorm<<<4096, 256, 0, stream>>>(cat_, 512, 64, sqb);
    for (int p = 0; p < 2; p++) {
        k_dist<64><<<dim3(8, 8, 8), 256, 0, stream>>>(cat_, 512, sqb, dist, p);
        k_select<<<2048, 256, 0, stream>>>(dist, idx, p);
    }
    k_gemm_pq<64, 64><<<dim3(256, 2), 256, 0, stream>>>(cat_, 512, wc2, bb2, pq);
    k_gather<<<4096, 256, 0, stream>>>(pq, idx, cat_, 6, 64);
    // layer 3 (64 -> 128)
    k_sqnorm<<<4096, 256, 0, stream>>>(cat_ + 64, 512, 64, sqb);
    for (int p = 0; p < 2; p++) {
        k_dist<64><<<dim3(8, 8, 8), 256, 0, stream>>>(cat_ + 64, 512, sqb, dist, p);
        k_select<<<2048, 256, 0, stream>>>(dist, idx, p);
    }
    k_gemm_pq<64, 128><<<dim3(256, 4), 256, 0, stream>>>(cat_ + 64, 512, wc3, bb3, pq);
    k_gather<<<8192, 256, 0, stream>>>(pq, idx, cat_, 7, 128);
    // layer 4 (128 -> 256)
    k_sqnorm<<<4096, 256, 0, stream>>>(cat_ + 128, 512, 128, sqb);
    for (int p = 0; p < 2; p++) {
        k_dist<128><<<dim3(8, 8, 8), 256, 0, stream>>>(cat_ + 128, 512, sqb, dist, p);
        k_select<<<2048, 256, 0, stream>>>(dist, idx, p);
    }
    k_gemm_pq<128, 256><<<dim3(256, 8), 256, 0, stream>>>(cat_ + 128, 512, wc4, bb4, pq);
    k_gather<<<16384, 256, 0, stream>>>(pq, idx, cat_, 8, 256);

    // pq now dead; pmax/pmin alias it
    k_init<<<512, 256, 0, stream>>>(colsum, colsq, pmax, pmin);
    k_fused_lin<<<dim3(8, 128), 256, 0, stream>>>(cat_, Wl, bl, colsum, colsq, pmax, pmin);
    k_bnpool<<<64, 256, 0, stream>>>(colsum, colsq, pmax, pmin, gl, betal, pooled);
    k_mlp1<<<32, 256, 0, stream>>>(pooled, Wm1, bm1, gm1, betam1, hbuf);
    k_mlp2<<<3, 256, 0, stream>>>(hbuf, Wm2, bm2, out);
}